// Round 1
// baseline (183.861 us; speedup 1.0000x reference)
//
#include <hip/hip_runtime.h>

// Problem constants (B=1, D=128, H=64, W=96, 4 levels, radius 4)
#define D 128
#define H0 64
#define W0 96
#define HW0 (H0 * W0)          // 6144
#define INV_SQRT_D 0.08838834764831843f

// Workspace layout (in floats)
#define OFF_F1T0 0
#define OFF_F2T0 786432
#define OFF_F1T1 1572864
#define OFF_F2T1 1769472
#define OFF_F1T2 1966080
#define OFF_F2T2 2015232
#define OFF_F1T3 2064384
#define OFF_F2T3 2076672
#define OFF_C1   2088960
#define OFF_C2   2092032
#define OFF_C3   2092800
// total ws use: 2092992 floats = 8.37 MB

// Output offsets (floats)
#define OUT_L0 0
#define OUT_L1 497664
#define OUT_L2 622080
#define OUT_L3 653184

// ---------------------------------------------------------------------------
// K1: transpose (D, HW0) -> (HW0, D) for both maps (blockIdx.z selects map)
// ---------------------------------------------------------------------------
__global__ __launch_bounds__(256) void k_transpose(const float* __restrict__ f1,
                                                   const float* __restrict__ f2,
                                                   float* __restrict__ ws) {
    __shared__ float tile[32][33];
    const float* in = (blockIdx.z == 0) ? f1 : f2;
    float* out = ws + ((blockIdx.z == 0) ? OFF_F1T0 : OFF_F2T0);
    const int p0 = blockIdx.x * 32;   // pixel tile
    const int d0 = blockIdx.y * 32;   // channel tile
    const int t = threadIdx.x;
    const int c = t & 31;             // fast index (lane-contiguous)
    const int r = t >> 5;             // 0..7
#pragma unroll
    for (int j = 0; j < 4; ++j) {
        int di = r + j * 8;
        tile[di][c] = in[(d0 + di) * HW0 + p0 + c];   // coalesced over p
    }
    __syncthreads();
#pragma unroll
    for (int j = 0; j < 4; ++j) {
        int pl = r + j * 8;
        out[(p0 + pl) * D + d0 + c] = tile[c][pl];    // coalesced over d
    }
}

// ---------------------------------------------------------------------------
// K2: all pyramid levels (1..3), both maps, from transposed level 0.
// Iterated 2x2 avg-pool == direct 2^l x 2^l window mean.
// ---------------------------------------------------------------------------
__global__ __launch_bounds__(256) void k_pools(float* __restrict__ ws) {
    const int PER_MAP = 196608 + 49152 + 12288;   // 258048
    int idx = blockIdx.x * 256 + threadIdx.x;
    if (idx >= 2 * PER_MAP) return;
    const int m = idx / PER_MAP;
    int r = idx % PER_MAP;
    int level;
    if (r < 196608) { level = 1; }
    else if (r < 245760) { level = 2; r -= 196608; }
    else { level = 3; r -= 245760; }
    const int Wl = W0 >> level;
    const int f = 1 << level;
    const int d = r & (D - 1);
    const int p = r >> 7;
    const int h = p / Wl, w = p % Wl;

    const float* src = ws + (m ? OFF_F2T0 : OFF_F1T0);
    const int f1offs[4] = {OFF_F1T0, OFF_F1T1, OFF_F1T2, OFF_F1T3};
    const int f2offs[4] = {OFF_F2T0, OFF_F2T1, OFF_F2T2, OFF_F2T3};
    float* dst = ws + (m ? f2offs[level] : f1offs[level]);

    float acc = 0.0f;
    for (int i = 0; i < f; ++i) {
        const float* row = src + ((h * f + i) * W0 + w * f) * D + d;
        for (int j = 0; j < f; ++j) acc += row[j * D];
    }
    dst[p * D + d] = acc / (float)(f * f);
}

// ---------------------------------------------------------------------------
// K3: coords resize (jax.image.resize 'linear', antialias=True) + /2^l scale.
// sample_f = (o+0.5)*f - 0.5; triangle kernel width f; per-axis renorm.
// ---------------------------------------------------------------------------
__global__ __launch_bounds__(256) void k_coords(const float* __restrict__ coords,
                                                float* __restrict__ ws) {
    int idx = blockIdx.x * 256 + threadIdx.x;
    if (idx >= 4032) return;
    int level, r = idx;
    if (r < 3072) { level = 1; }
    else if (r < 3840) { level = 2; r -= 3072; }
    else { level = 3; r -= 3840; }
    const int Hl = H0 >> level, Wl = W0 >> level;
    const int f = 1 << level;
    const float ff = (float)f;
    const int npix = Hl * Wl;
    const int ch = r / npix;
    const int rem = r % npix;
    const int ho = rem / Wl, wo = rem % Wl;

    const float sfy = (ho + 0.5f) * ff - 0.5f;
    const float sfx = (wo + 0.5f) * ff - 0.5f;
    int ylo = max(0, (int)ceilf(sfy - ff));
    int yhi = min(H0 - 1, (int)floorf(sfy + ff));
    int xlo = max(0, (int)ceilf(sfx - ff));
    int xhi = min(W0 - 1, (int)floorf(sfx + ff));

    float acc = 0.0f, wsum_y = 0.0f, wsum_x = 0.0f;
    for (int iy = ylo; iy <= yhi; ++iy) {
        float wy = 1.0f - fabsf(sfy - (float)iy) / ff;
        if (wy < 0.0f) wy = 0.0f;
        wsum_y += wy;
        float rowacc = 0.0f;
        for (int ix = xlo; ix <= xhi; ++ix) {
            float wx = 1.0f - fabsf(sfx - (float)ix) / ff;
            if (wx < 0.0f) wx = 0.0f;
            if (iy == ylo) wsum_x += wx;
            rowacc += wx * coords[ch * HW0 + iy * W0 + ix];
        }
        acc += wy * rowacc;
    }
    float val = acc / (wsum_y * wsum_x) / ff;   // resize then /2^level

    const int coffs[4] = {0, OFF_C1, OFF_C2, OFF_C3};
    ws[coffs[level] + ch * npix + ho * Wl + wo] = val;
}

// ---------------------------------------------------------------------------
// K4: fused correlation for all 4 levels. One wave per pixel; lanes over D
// (2 channels/lane). 81 k-iterations, 8 coalesced 256B loads each, bilinear
// combine, 6-step shfl_xor reduce, lane 0 stores.
// ---------------------------------------------------------------------------
__global__ __launch_bounds__(256) void k_corr(const float* __restrict__ coords0,
                                              const float* __restrict__ ws,
                                              float* __restrict__ out) {
    const int gw = blockIdx.x * 4 + (threadIdx.x >> 6);
    const int lane = threadIdx.x & 63;
    if (gw >= 8160) return;

    int level, p;
    if (gw < 6144)       { level = 0; p = gw; }
    else if (gw < 7680)  { level = 1; p = gw - 6144; }
    else if (gw < 8064)  { level = 2; p = gw - 7680; }
    else                 { level = 3; p = gw - 8064; }

    const int Hl = H0 >> level, Wl = W0 >> level;
    const int npix = Hl * Wl;

    const int f1offs[4] = {OFF_F1T0, OFF_F1T1, OFF_F1T2, OFF_F1T3};
    const int f2offs[4] = {OFF_F2T0, OFF_F2T1, OFF_F2T2, OFF_F2T3};
    const int coffs[4]  = {0, OFF_C1, OFF_C2, OFF_C3};
    const int outoffs[4] = {OUT_L0, OUT_L1, OUT_L2, OUT_L3};

    const float* f1t = ws + f1offs[level];
    const float* f2t = ws + f2offs[level];
    const float* cp = (level == 0) ? coords0 : (ws + coffs[level]);
    float* outp = out + outoffs[level];

    const float cx = cp[p];
    const float cy = cp[npix + p];
    const float f1a = f1t[p * D + lane];
    const float f1b = f1t[p * D + 64 + lane];
    const float Wm1 = (float)(Wl - 1), Hm1 = (float)(Hl - 1);

    int k = 0;
    for (int dx = -4; dx <= 4; ++dx) {
        float x = fminf(fmaxf(cx + (float)dx, 0.0f), Wm1);
        int x0 = (int)x;                       // floor (x >= 0)
        int x1 = min(x0 + 1, Wl - 1);
        float wx1 = x - (float)x0, wx0 = 1.0f - wx1;
        for (int dy = -4; dy <= 4; ++dy) {
            float y = fminf(fmaxf(cy + (float)dy, 0.0f), Hm1);
            int y0 = (int)y;
            int y1 = min(y0 + 1, Hl - 1);
            float wy1 = y - (float)y0, wy0 = 1.0f - wy1;

            const float* b00 = f2t + (y0 * Wl + x0) * D;
            const float* b01 = f2t + (y0 * Wl + x1) * D;
            const float* b10 = f2t + (y1 * Wl + x0) * D;
            const float* b11 = f2t + (y1 * Wl + x1) * D;
            const float w00 = wx0 * wy0, w01 = wx1 * wy0;
            const float w10 = wx0 * wy1, w11 = wx1 * wy1;

            float va = w00 * b00[lane]      + w01 * b01[lane]
                     + w10 * b10[lane]      + w11 * b11[lane];
            float vb = w00 * b00[lane + 64] + w01 * b01[lane + 64]
                     + w10 * b10[lane + 64] + w11 * b11[lane + 64];
            float s = f1a * va + f1b * vb;
#pragma unroll
            for (int off = 32; off; off >>= 1) s += __shfl_xor(s, off, 64);
            if (lane == 0) outp[k * npix + p] = s * INV_SQRT_D;
            ++k;
        }
    }
}

// ---------------------------------------------------------------------------
extern "C" void kernel_launch(void* const* d_in, const int* in_sizes, int n_in,
                              void* d_out, int out_size, void* d_ws, size_t ws_size,
                              hipStream_t stream) {
    const float* fmap1  = (const float*)d_in[0];
    const float* fmap2  = (const float*)d_in[1];
    const float* coords = (const float*)d_in[2];
    float* out = (float*)d_out;
    float* ws = (float*)d_ws;

    dim3 blk(256);
    k_transpose<<<dim3(HW0 / 32, D / 32, 2), blk, 0, stream>>>(fmap1, fmap2, ws);
    k_pools<<<dim3((2 * 258048) / 256), blk, 0, stream>>>(ws);
    k_coords<<<dim3(16), blk, 0, stream>>>(coords, ws);
    k_corr<<<dim3(2040), blk, 0, stream>>>(coords, ws, out);
}

// Round 2
// 150.816 us; speedup vs baseline: 1.2191x; 1.2191x over previous
//
#include <hip/hip_runtime.h>

// Problem constants (B=1, D=128, H=64, W=96, 4 levels, radius 4)
#define D 128
#define H0 64
#define W0 96
#define HW0 (H0 * W0)          // 6144
#define INV_SQRT_D 0.08838834764831843f

// Workspace layout (in floats)
#define OFF_F1T0 0
#define OFF_F2T0 786432
#define OFF_F1T1 1572864
#define OFF_F2T1 1769472
#define OFF_F1T2 1966080
#define OFF_F2T2 2015232
#define OFF_F1T3 2064384
#define OFF_F2T3 2076672
#define OFF_C1   2088960
#define OFF_C2   2092032
#define OFF_C3   2092800

// Output offsets (floats)
#define OUT_L0 0
#define OUT_L1 497664
#define OUT_L2 622080
#define OUT_L3 653184

// ---------------------------------------------------------------------------
// K1: transpose (D, HW0) -> (HW0, D) for both maps (blockIdx.z selects map)
// ---------------------------------------------------------------------------
__global__ __launch_bounds__(256) void k_transpose(const float* __restrict__ f1,
                                                   const float* __restrict__ f2,
                                                   float* __restrict__ ws) {
    __shared__ float tile[32][33];
    const float* in = (blockIdx.z == 0) ? f1 : f2;
    float* out = ws + ((blockIdx.z == 0) ? OFF_F1T0 : OFF_F2T0);
    const int p0 = blockIdx.x * 32;
    const int d0 = blockIdx.y * 32;
    const int t = threadIdx.x;
    const int c = t & 31;
    const int r = t >> 5;
#pragma unroll
    for (int j = 0; j < 4; ++j) {
        int di = r + j * 8;
        tile[di][c] = in[(d0 + di) * HW0 + p0 + c];
    }
    __syncthreads();
#pragma unroll
    for (int j = 0; j < 4; ++j) {
        int pl = r + j * 8;
        out[(p0 + pl) * D + d0 + c] = tile[c][pl];
    }
}

// ---------------------------------------------------------------------------
// K2: fused pools (levels 1..3 of both maps) + coords resize. Blocks
// [0,2016) do pooling, [2016,2032) do the antialiased coords resize.
// ---------------------------------------------------------------------------
__global__ __launch_bounds__(256) void k_prep(const float* __restrict__ coords,
                                              float* __restrict__ ws) {
    const int PER_MAP = 196608 + 49152 + 12288;   // 258048
    if (blockIdx.x < 2016) {
        int idx = blockIdx.x * 256 + threadIdx.x;
        if (idx >= 2 * PER_MAP) return;
        const int m = idx / PER_MAP;
        int r = idx % PER_MAP;
        int level;
        if (r < 196608) { level = 1; }
        else if (r < 245760) { level = 2; r -= 196608; }
        else { level = 3; r -= 245760; }
        const int Wl = W0 >> level;
        const int f = 1 << level;
        const int d = r & (D - 1);
        const int p = r >> 7;
        const int h = p / Wl, w = p % Wl;

        const float* src = ws + (m ? OFF_F2T0 : OFF_F1T0);
        const int f1offs[4] = {OFF_F1T0, OFF_F1T1, OFF_F1T2, OFF_F1T3};
        const int f2offs[4] = {OFF_F2T0, OFF_F2T1, OFF_F2T2, OFF_F2T3};
        float* dst = ws + (m ? f2offs[level] : f1offs[level]);

        float acc = 0.0f;
        for (int i = 0; i < f; ++i) {
            const float* row = src + ((h * f + i) * W0 + w * f) * D + d;
            for (int j = 0; j < f; ++j) acc += row[j * D];
        }
        dst[p * D + d] = acc / (float)(f * f);
    } else {
        int idx = (blockIdx.x - 2016) * 256 + threadIdx.x;
        if (idx >= 4032) return;
        int level, r = idx;
        if (r < 3072) { level = 1; }
        else if (r < 3840) { level = 2; r -= 3072; }
        else { level = 3; r -= 3840; }
        const int Hl = H0 >> level, Wl = W0 >> level;
        const int f = 1 << level;
        const float ff = (float)f;
        const int npix = Hl * Wl;
        const int ch = r / npix;
        const int rem = r % npix;
        const int ho = rem / Wl, wo = rem % Wl;

        const float sfy = (ho + 0.5f) * ff - 0.5f;
        const float sfx = (wo + 0.5f) * ff - 0.5f;
        int ylo = max(0, (int)ceilf(sfy - ff));
        int yhi = min(H0 - 1, (int)floorf(sfy + ff));
        int xlo = max(0, (int)ceilf(sfx - ff));
        int xhi = min(W0 - 1, (int)floorf(sfx + ff));

        float acc = 0.0f, wsum_y = 0.0f, wsum_x = 0.0f;
        for (int iy = ylo; iy <= yhi; ++iy) {
            float wy = 1.0f - fabsf(sfy - (float)iy) / ff;
            if (wy < 0.0f) wy = 0.0f;
            wsum_y += wy;
            float rowacc = 0.0f;
            for (int ix = xlo; ix <= xhi; ++ix) {
                float wx = 1.0f - fabsf(sfx - (float)ix) / ff;
                if (wx < 0.0f) wx = 0.0f;
                if (iy == ylo) wsum_x += wx;
                rowacc += wx * coords[ch * HW0 + iy * W0 + ix];
            }
            acc += wy * rowacc;
        }
        float val = acc / (wsum_y * wsum_x) / ff;

        const int coffs[4] = {0, OFF_C1, OFF_C2, OFF_C3};
        ws[coffs[level] + ch * npix + ho * Wl + wo] = val;
    }
}

// ---------------------------------------------------------------------------
// K3: grid-dot correlation. One block(128) per pixel. Compute the 10x10 grid
// of integer-position dot products (lane <-> grid point, f2 patch staged in
// LDS as [d][g] stride 101 = conflict-free), then 81 taps = 4 MACs each.
// ---------------------------------------------------------------------------
__global__ __launch_bounds__(128) void k_corr_grid(const float* __restrict__ coords0,
                                                   const float* __restrict__ ws,
                                                   float* __restrict__ out) {
    __shared__ float patch[64 * 101];   // [d_local][g], stride 101
    __shared__ float f1s[D];
    __shared__ float dotbuf[100];
    __shared__ int qidx[100];
    __shared__ float cxy[2];

    const int b = blockIdx.x;
    int level, p;
    if (b < 6144)      { level = 0; p = b; }
    else if (b < 7680) { level = 1; p = b - 6144; }
    else if (b < 8064) { level = 2; p = b - 7680; }
    else               { level = 3; p = b - 8064; }

    const int Hl = H0 >> level, Wl = W0 >> level;
    const int npix = Hl * Wl;

    const int f1offs[4] = {OFF_F1T0, OFF_F1T1, OFF_F1T2, OFF_F1T3};
    const int f2offs[4] = {OFF_F2T0, OFF_F2T1, OFF_F2T2, OFF_F2T3};
    const int coffs[4]  = {0, OFF_C1, OFF_C2, OFF_C3};
    const int outoffs[4] = {OUT_L0, OUT_L1, OUT_L2, OUT_L3};

    const float* f1t = ws + f1offs[level];
    const float* f2t = ws + f2offs[level];
    const float* cp = (level == 0) ? coords0 : (ws + coffs[level]);
    float* outp = out + outoffs[level];

    const int t = threadIdx.x;
    if (t == 0) { cxy[0] = cp[p]; cxy[1] = cp[npix + p]; }
    f1s[t] = f1t[p * D + t];
    __syncthreads();

    const float cx = cxy[0], cy = cxy[1];
    const int fx = (int)floorf(cx), fy = (int)floorf(cy);
    if (t < 100) {
        int gy = t / 10, gx = t - gy * 10;
        int iy = min(max(fy - 4 + gy, 0), Hl - 1);
        int ix = min(max(fx - 4 + gx, 0), Wl - 1);
        qidx[t] = iy * Wl + ix;
    }
    __syncthreads();

    float dot = 0.0f;
#pragma unroll
    for (int phase = 0; phase < 2; ++phase) {
        // stage 100 x 64 patch slice: 3200 float2 / 128 threads = 25 iters
#pragma unroll 5
        for (int it = 0; it < 25; ++it) {
            int e = t + it * 128;
            int q = e >> 5;
            int dp = e & 31;
            float2 v = *(const float2*)(f2t + qidx[q] * D + phase * 64 + dp * 2);
            patch[(dp * 2) * 101 + q] = v.x;
            patch[(dp * 2 + 1) * 101 + q] = v.y;
        }
        __syncthreads();
        if (t < 100) {
            const float* fp = f1s + phase * 64;
            float d0 = 0.f, d1 = 0.f, d2 = 0.f, d3 = 0.f;
#pragma unroll
            for (int d = 0; d < 64; d += 4) {
                d0 += fp[d]     * patch[d * 101 + t];
                d1 += fp[d + 1] * patch[(d + 1) * 101 + t];
                d2 += fp[d + 2] * patch[(d + 2) * 101 + t];
                d3 += fp[d + 3] * patch[(d + 3) * 101 + t];
            }
            dot += (d0 + d1) + (d2 + d3);
        }
        __syncthreads();
    }
    if (t < 100) dotbuf[t] = dot;
    __syncthreads();

    if (t < 81) {
        const int dxi = t / 9;
        const int dyi = t - dxi * 9;
        const float Wm1 = (float)(Wl - 1), Hm1 = (float)(Hl - 1);
        float x = fminf(fmaxf(cx + (float)(dxi - 4), 0.0f), Wm1);
        float y = fminf(fmaxf(cy + (float)(dyi - 4), 0.0f), Hm1);
        float wx1 = x - floorf(x), wx0 = 1.0f - wx1;
        float wy1 = y - floorf(y), wy0 = 1.0f - wy1;
        int g00 = dyi * 10 + dxi;
        float v = wx0 * wy0 * dotbuf[g00]
                + wx1 * wy0 * dotbuf[g00 + 1]
                + wx0 * wy1 * dotbuf[g00 + 10]
                + wx1 * wy1 * dotbuf[g00 + 11];
        outp[t * npix + p] = v * INV_SQRT_D;
    }
}

// ---------------------------------------------------------------------------
extern "C" void kernel_launch(void* const* d_in, const int* in_sizes, int n_in,
                              void* d_out, int out_size, void* d_ws, size_t ws_size,
                              hipStream_t stream) {
    const float* fmap1  = (const float*)d_in[0];
    const float* fmap2  = (const float*)d_in[1];
    const float* coords = (const float*)d_in[2];
    float* out = (float*)d_out;
    float* ws = (float*)d_ws;

    dim3 blk(256);
    k_transpose<<<dim3(HW0 / 32, D / 32, 2), blk, 0, stream>>>(fmap1, fmap2, ws);
    k_prep<<<dim3(2032), blk, 0, stream>>>(coords, ws);
    k_corr_grid<<<dim3(8160), dim3(128), 0, stream>>>(coords, ws, out);
}

// Round 3
// 148.979 us; speedup vs baseline: 1.2341x; 1.0123x over previous
//
#include <hip/hip_runtime.h>

// Problem constants (B=1, D=128, H=64, W=96, 4 levels, radius 4)
#define D 128
#define H0 64
#define W0 96
#define HW0 6144
#define INV_SQRT_D 0.08838834764831843f

// Workspace layout (float offsets)
#define OFF_F1T0 0
#define OFF_F2T0 786432
#define OFF_F1T1 1572864
#define OFF_F2T1 1769472
#define OFF_F1T2 1966080
#define OFF_F2T2 2015232
#define OFF_F1T3 2064384
#define OFF_F2T3 2076672
#define OFF_C1   2088960
#define OFF_C2   2092032
#define OFF_C3   2092800
#define OFF_G    2092992   // 8160*100 floats; ws use ends at 11.64 MB

// Output offsets (floats)
#define OUT_L0 0
#define OUT_L1 497664
#define OUT_L2 622080
#define OUT_L3 653184

__device__ __forceinline__ void gp_to_level(int gp, int& level, int& p) {
    if (gp < 6144)      { level = 0; p = gp; }
    else if (gp < 7680) { level = 1; p = gp - 6144; }
    else if (gp < 8064) { level = 2; p = gp - 7680; }
    else                { level = 3; p = gp - 8064; }
}

// ---------------------------------------------------------------------------
// K1: fused tile transpose + all pool levels (blocks 0..191) + coords resize
// (blocks 192..207). Each tile block: 8x8 px * 128 d staged in LDS once.
// ---------------------------------------------------------------------------
__global__ __launch_bounds__(256) void k_prep(const float* __restrict__ f1,
                                              const float* __restrict__ f2,
                                              const float* __restrict__ coords,
                                              float* __restrict__ ws) {
    const int b = blockIdx.x;
    const int t = threadIdx.x;
    if (b < 192) {
        __shared__ float T[64 * 133];   // [pixel_local][d], stride 133 (odd: conflict-free)
        const int m = b / 96;
        const int tix = b - m * 96;
        const int tr = tix / 12, tc = tix - (tix / 12) * 12;
        const float* in = m ? f2 : f1;

        // load tile: lane l = local pixel, 4 d's per pass
        const int l = t & 63;
        const int gbase = (tr * 8 + (l >> 3)) * W0 + tc * 8 + (l & 7);
        for (int pass = 0; pass < 32; ++pass) {
            int d = pass * 4 + (t >> 6);
            T[l * 133 + d] = in[d * HW0 + gbase];
        }
        __syncthreads();

        // transposed L0 out: (pl, c) coalesced over c
        float* o0 = ws + (m ? OFF_F2T0 : OFF_F1T0);
        for (int pass = 0; pass < 32; ++pass) {
            int e = t + pass * 256;
            int pl = e >> 7, c = e & 127;
            int gp = (tr * 8 + (pl >> 3)) * W0 + tc * 8 + (pl & 7);
            o0[gp * D + c] = T[pl * 133 + c];
        }
        // L1 pool: 16 px * 128 d
        float* o1 = ws + (m ? OFF_F2T1 : OFF_F1T1);
        for (int pass = 0; pass < 8; ++pass) {
            int e = t + pass * 256;
            int d = e & 127, p1 = e >> 7;           // p1 0..15
            int i1 = p1 >> 2, j1 = p1 & 3;
            int l00 = (i1 * 2) * 8 + j1 * 2;
            float v = T[l00 * 133 + d] + T[(l00 + 1) * 133 + d]
                    + T[(l00 + 8) * 133 + d] + T[(l00 + 9) * 133 + d];
            int gp1 = (tr * 4 + i1) * 48 + tc * 4 + j1;
            o1[gp1 * D + d] = 0.25f * v;
        }
        // L2 pool: 4 px * 128 d
        float* o2 = ws + (m ? OFF_F2T2 : OFF_F1T2);
        for (int pass = 0; pass < 2; ++pass) {
            int e = t + pass * 256;
            int d = e & 127, p2 = e >> 7;           // p2 0..3
            int i2 = p2 >> 1, j2 = p2 & 1;
            float acc = 0.0f;
#pragma unroll
            for (int a = 0; a < 4; ++a)
#pragma unroll
                for (int c2 = 0; c2 < 4; ++c2)
                    acc += T[((i2 * 4 + a) * 8 + j2 * 4 + c2) * 133 + d];
            int gp2 = (tr * 2 + i2) * 24 + tc * 2 + j2;
            o2[gp2 * D + d] = acc * 0.0625f;
        }
        // L3 pool: 1 px * 128 d
        float* o3 = ws + (m ? OFF_F2T3 : OFF_F1T3);
        if (t < 128) {
            float acc = 0.0f;
            for (int l2 = 0; l2 < 64; ++l2) acc += T[l2 * 133 + t];
            o3[(tr * 12 + tc) * D + t] = acc * 0.015625f;
        }
    } else {
        // coords resize (jax.image.resize linear, antialias=True) + /2^l
        int idx = (b - 192) * 256 + t;
        if (idx >= 4032) return;
        int level, r = idx;
        if (r < 3072) { level = 1; }
        else if (r < 3840) { level = 2; r -= 3072; }
        else { level = 3; r -= 3840; }
        const int Hl = H0 >> level, Wl = W0 >> level;
        const float ff = (float)(1 << level);
        const int npix = Hl * Wl;
        const int ch = r / npix;
        const int rem = r - ch * npix;
        const int ho = rem / Wl, wo = rem - (rem / Wl) * Wl;

        const float sfy = (ho + 0.5f) * ff - 0.5f;
        const float sfx = (wo + 0.5f) * ff - 0.5f;
        int ylo = max(0, (int)ceilf(sfy - ff));
        int yhi = min(H0 - 1, (int)floorf(sfy + ff));
        int xlo = max(0, (int)ceilf(sfx - ff));
        int xhi = min(W0 - 1, (int)floorf(sfx + ff));

        float acc = 0.0f, wsum_y = 0.0f, wsum_x = 0.0f;
        for (int iy = ylo; iy <= yhi; ++iy) {
            float wy = fmaxf(1.0f - fabsf(sfy - (float)iy) / ff, 0.0f);
            wsum_y += wy;
            float rowacc = 0.0f;
            for (int ix = xlo; ix <= xhi; ++ix) {
                float wx = fmaxf(1.0f - fabsf(sfx - (float)ix) / ff, 0.0f);
                if (iy == ylo) wsum_x += wx;
                rowacc += wx * coords[ch * HW0 + iy * W0 + ix];
            }
            acc += wy * rowacc;
        }
        float val = acc / (wsum_y * wsum_x) / ff;
        const int coffs[4] = {0, OFF_C1, OFF_C2, OFF_C3};
        ws[coffs[level] + ch * npix + ho * Wl + wo] = val;
    }
}

// ---------------------------------------------------------------------------
// K2: grid dots. One block(128) per pixel. Patch staged [g][d] stride 68
// (16B-aligned, bank-balanced), read back ds_read_b128; f1 via uniform
// (scalar) loads; result G[gp*100+g] stored coalesced.
// ---------------------------------------------------------------------------
__global__ __launch_bounds__(128) void k_dots(const float* __restrict__ coords0,
                                              float* __restrict__ ws) {
    __shared__ float patch[100 * 68];
    __shared__ int qidx[100];

    const int b = blockIdx.x;
    int level, p;
    gp_to_level(b, level, p);
    const int Hl = H0 >> level, Wl = W0 >> level;
    const int npix = Hl * Wl;

    const int f1offs[4] = {OFF_F1T0, OFF_F1T1, OFF_F1T2, OFF_F1T3};
    const int f2offs[4] = {OFF_F2T0, OFF_F2T1, OFF_F2T2, OFF_F2T3};
    const int coffs[4]  = {0, OFF_C1, OFF_C2, OFF_C3};

    const float* f2t = ws + f2offs[level];
    const float* f1p = ws + f1offs[level] + p * D;   // uniform -> scalar loads
    const float* cp = (level == 0) ? coords0 : (ws + coffs[level]);

    const float cx = cp[p];          // uniform
    const float cy = cp[npix + p];   // uniform
    const int fx = (int)floorf(cx), fy = (int)floorf(cy);
    const int t = threadIdx.x;

    if (t < 100) {
        int gy = t / 10, gx = t - (t / 10) * 10;
        int iy = min(max(fy - 4 + gy, 0), Hl - 1);
        int ix = min(max(fx - 4 + gx, 0), Wl - 1);
        qidx[t] = iy * Wl + ix;
    }
    __syncthreads();

    float acc = 0.0f;
#pragma unroll
    for (int ph = 0; ph < 2; ++ph) {
        // stage 100 rows x 64 floats as float4: 1600 float4 / 128 thr
        for (int it = 0; it < 13; ++it) {
            int e = t + it * 128;
            if (e < 1600) {
                int q = e >> 4, dp = e & 15;
                float4 v = *(const float4*)(f2t + qidx[q] * D + ph * 64 + dp * 4);
                *(float4*)&patch[q * 68 + dp * 4] = v;
            }
        }
        __syncthreads();
        if (t < 100) {
            const float* pr = &patch[t * 68];
            const float* fp = f1p + ph * 64;
            float a0 = 0.f, a1 = 0.f, a2 = 0.f, a3 = 0.f;
#pragma unroll
            for (int d4 = 0; d4 < 16; ++d4) {
                float4 a = *(const float4*)(fp + d4 * 4);    // s_load (uniform)
                float4 pv = *(const float4*)(pr + d4 * 4);   // ds_read_b128
                a0 += a.x * pv.x; a1 += a.y * pv.y;
                a2 += a.z * pv.z; a3 += a.w * pv.w;
            }
            acc += (a0 + a1) + (a2 + a3);
        }
        __syncthreads();
    }
    if (t < 100) ws[OFF_G + b * 100 + t] = acc;
}

// ---------------------------------------------------------------------------
// K3: combine. Block = 64 consecutive pixels; G staged in LDS; each wave
// handles one k at a time over 64 consecutive p -> fully coalesced stores.
// ---------------------------------------------------------------------------
__global__ __launch_bounds__(256) void k_combine(const float* __restrict__ coords0,
                                                 const float* __restrict__ ws,
                                                 float* __restrict__ out) {
    __shared__ float Gs[64 * 101];
    __shared__ float cxs[64], cys[64];

    const int b = blockIdx.x;
    const int gp0 = b * 64;
    const int t = threadIdx.x;
    const int coffs[4]  = {0, OFF_C1, OFF_C2, OFF_C3};
    const int outoffs[4] = {OUT_L0, OUT_L1, OUT_L2, OUT_L3};

    for (int it = 0; it < 25; ++it) {
        int e = t + it * 256;                 // 0..6399
        int px = e / 100, g = e - px * 100;
        if (gp0 + px < 8160) Gs[px * 101 + g] = ws[OFF_G + (gp0 + px) * 100 + g];
    }
    if (t < 64 && gp0 + t < 8160) {
        int level, p;
        gp_to_level(gp0 + t, level, p);
        const float* cp = (level == 0) ? coords0 : (ws + coffs[level]);
        int npix = (H0 >> level) * (W0 >> level);
        cxs[t] = cp[p];
        cys[t] = cp[npix + p];
    }
    __syncthreads();

    const int px = t & 63;
    const int gp = gp0 + px;
    if (gp >= 8160) return;
    int level, p;
    gp_to_level(gp, level, p);
    const int Hl = H0 >> level, Wl = W0 >> level;
    const int npix = Hl * Wl;
    float* outp = out + outoffs[level] + p;
    const float cx = cxs[px], cy = cys[px];
    const float Wm1 = (float)(Wl - 1), Hm1 = (float)(Hl - 1);
    const float* Gp = &Gs[px * 101];

    for (int k = t >> 6; k < 81; k += 4) {
        int dxi = k / 9, dyi = k - (k / 9) * 9;
        float x = fminf(fmaxf(cx + (float)(dxi - 4), 0.0f), Wm1);
        float y = fminf(fmaxf(cy + (float)(dyi - 4), 0.0f), Hm1);
        float wx1 = x - floorf(x), wx0 = 1.0f - wx1;
        float wy1 = y - floorf(y), wy0 = 1.0f - wy1;
        int g00 = dyi * 10 + dxi;
        float v = wx0 * wy0 * Gp[g00]      + wx1 * wy0 * Gp[g00 + 1]
                + wx0 * wy1 * Gp[g00 + 10] + wx1 * wy1 * Gp[g00 + 11];
        outp[k * npix] = v * INV_SQRT_D;
    }
}

// ---------------------------------------------------------------------------
extern "C" void kernel_launch(void* const* d_in, const int* in_sizes, int n_in,
                              void* d_out, int out_size, void* d_ws, size_t ws_size,
                              hipStream_t stream) {
    const float* fmap1  = (const float*)d_in[0];
    const float* fmap2  = (const float*)d_in[1];
    const float* coords = (const float*)d_in[2];
    float* out = (float*)d_out;
    float* ws = (float*)d_ws;

    k_prep<<<dim3(208), dim3(256), 0, stream>>>(fmap1, fmap2, coords, ws);
    k_dots<<<dim3(8160), dim3(128), 0, stream>>>(coords, ws);
    k_combine<<<dim3(128), dim3(256), 0, stream>>>(coords, ws, out);
}

// Round 4
// 130.676 us; speedup vs baseline: 1.4070x; 1.1401x over previous
//
#include <hip/hip_runtime.h>

// Problem constants (B=1, D=128, H=64, W=96, 4 levels, radius 4)
#define D 128
#define H0 64
#define W0 96
#define HW0 6144
#define INV_SQRT_D 0.08838834764831843f

// Workspace layout (float offsets)
#define OFF_F1T0 0
#define OFF_F2T0 786432
#define OFF_F1T1 1572864
#define OFF_F2T1 1769472
#define OFF_F1T2 1966080
#define OFF_F2T2 2015232
#define OFF_F1T3 2064384
#define OFF_F2T3 2076672
#define OFF_C1   2088960
#define OFF_C2   2092032
#define OFF_C3   2092800
#define OFF_G    2092992   // 8160*100 floats

// Output offsets (floats)
#define OUT_L0 0
#define OUT_L1 497664
#define OUT_L2 622080
#define OUT_L3 653184

__device__ __forceinline__ void gp_to_level(int gp, int& level, int& p) {
    if (gp < 6144)      { level = 0; p = gp; }
    else if (gp < 7680) { level = 1; p = gp - 6144; }
    else if (gp < 8064) { level = 2; p = gp - 7680; }
    else                { level = 3; p = gp - 8064; }
}

// ---------------------------------------------------------------------------
// K1: fused tile transpose + pools (blocks 0..383, d-split) + coords resize
// (blocks 384..399).
// ---------------------------------------------------------------------------
__global__ __launch_bounds__(256) void k_prep(const float* __restrict__ f1,
                                              const float* __restrict__ f2,
                                              const float* __restrict__ coords,
                                              float* __restrict__ ws) {
    const int b = blockIdx.x;
    const int t = threadIdx.x;
    if (b < 384) {
        __shared__ float T[64 * 69];    // [pixel_local][d_local], stride 69
        const int m = b / 192;
        const int rb = b - m * 192;
        const int tix = rb >> 1;        // 0..95
        const int dh = rb & 1;          // d half
        const int tr = tix / 12, tc = tix - (tix / 12) * 12;
        const float* in = (m ? f2 : f1) + dh * 64 * HW0;

        const int l = t & 63;
        const int gbase = (tr * 8 + (l >> 3)) * W0 + tc * 8 + (l & 7);
#pragma unroll 4
        for (int pass = 0; pass < 16; ++pass) {
            int d = pass * 4 + (t >> 6);
            T[l * 69 + d] = in[d * HW0 + gbase];
        }
        __syncthreads();

        float* o0 = ws + (m ? OFF_F2T0 : OFF_F1T0) + dh * 64;
#pragma unroll 4
        for (int pass = 0; pass < 16; ++pass) {
            int e = t + pass * 256;
            int pl = e >> 6, c = e & 63;
            int gp = (tr * 8 + (pl >> 3)) * W0 + tc * 8 + (pl & 7);
            o0[gp * D + c] = T[pl * 69 + c];
        }
        float* o1 = ws + (m ? OFF_F2T1 : OFF_F1T1) + dh * 64;
#pragma unroll
        for (int pass = 0; pass < 4; ++pass) {
            int e = t + pass * 256;
            int d = e & 63, p1 = e >> 6;            // p1 0..15
            int i1 = p1 >> 2, j1 = p1 & 3;
            int l00 = (i1 * 2) * 8 + j1 * 2;
            float v = T[l00 * 69 + d] + T[(l00 + 1) * 69 + d]
                    + T[(l00 + 8) * 69 + d] + T[(l00 + 9) * 69 + d];
            o1[((tr * 4 + i1) * 48 + tc * 4 + j1) * D + d] = 0.25f * v;
        }
        float* o2 = ws + (m ? OFF_F2T2 : OFF_F1T2) + dh * 64;
        {
            int d = t & 63, p2 = t >> 6;            // p2 0..3
            int i2 = p2 >> 1, j2 = p2 & 1;
            float acc = 0.0f;
#pragma unroll
            for (int a = 0; a < 4; ++a)
#pragma unroll
                for (int c2 = 0; c2 < 4; ++c2)
                    acc += T[((i2 * 4 + a) * 8 + j2 * 4 + c2) * 69 + d];
            o2[((tr * 2 + i2) * 24 + tc * 2 + j2) * D + d] = acc * 0.0625f;
        }
        float* o3 = ws + (m ? OFF_F2T3 : OFF_F1T3) + dh * 64;
        if (t < 64) {
            float acc = 0.0f;
            for (int l2 = 0; l2 < 64; ++l2) acc += T[l2 * 69 + t];
            o3[(tr * 12 + tc) * D + t] = acc * 0.015625f;
        }
    } else {
        // coords resize (jax.image.resize linear, antialias=True) + /2^l
        int idx = (b - 384) * 256 + t;
        if (idx >= 4032) return;
        int level, r = idx;
        if (r < 3072) { level = 1; }
        else if (r < 3840) { level = 2; r -= 3072; }
        else { level = 3; r -= 3840; }
        const int Hl = H0 >> level, Wl = W0 >> level;
        const float ff = (float)(1 << level);
        const int npix = Hl * Wl;
        const int ch = r / npix;
        const int rem = r - ch * npix;
        const int ho = rem / Wl, wo = rem - (rem / Wl) * Wl;

        const float sfy = (ho + 0.5f) * ff - 0.5f;
        const float sfx = (wo + 0.5f) * ff - 0.5f;
        int ylo = max(0, (int)ceilf(sfy - ff));
        int yhi = min(H0 - 1, (int)floorf(sfy + ff));
        int xlo = max(0, (int)ceilf(sfx - ff));
        int xhi = min(W0 - 1, (int)floorf(sfx + ff));

        float acc = 0.0f, wsum_y = 0.0f, wsum_x = 0.0f;
        for (int iy = ylo; iy <= yhi; ++iy) {
            float wy = fmaxf(1.0f - fabsf(sfy - (float)iy) / ff, 0.0f);
            wsum_y += wy;
            float rowacc = 0.0f;
            for (int ix = xlo; ix <= xhi; ++ix) {
                float wx = fmaxf(1.0f - fabsf(sfx - (float)ix) / ff, 0.0f);
                if (iy == ylo) wsum_x += wx;
                rowacc += wx * coords[ch * HW0 + iy * W0 + ix];
            }
            acc += wy * rowacc;
        }
        float val = acc / (wsum_y * wsum_x) / ff;
        const int coffs[4] = {0, OFF_C1, OFF_C2, OFF_C3};
        ws[coffs[level] + ch * npix + ho * Wl + wo] = val;
    }
}

// ---------------------------------------------------------------------------
// K2: grid dots, register-only. Half-wave (32 lanes) = one (pixel, g) dot
// per iteration: lane holds 4 d's; one coalesced float4 covers the 512B f2
// row; f1 float4 loaded once; 5-step shfl_xor reduce. No LDS, no barriers.
// Block(256) = 2 adjacent pixels (8 half-waves, 25 iters each).
// ---------------------------------------------------------------------------
__global__ __launch_bounds__(256) void k_dots(const float* __restrict__ coords0,
                                              float* __restrict__ ws) {
    const int t = threadIdx.x;
    const int hw = t >> 5;              // 0..7
    const int ln = t & 31;
    const int gp = blockIdx.x * 2 + (hw >> 2);

    int level, p;
    gp_to_level(gp, level, p);
    const int Hl = H0 >> level, Wl = W0 >> level;
    const int npix = Hl * Wl;

    const int f1offs[4] = {OFF_F1T0, OFF_F1T1, OFF_F1T2, OFF_F1T3};
    const int f2offs[4] = {OFF_F2T0, OFF_F2T1, OFF_F2T2, OFF_F2T3};
    const int coffs[4]  = {0, OFF_C1, OFF_C2, OFF_C3};

    const float* f2t = ws + f2offs[level];
    const float* cp = (level == 0) ? coords0 : (ws + coffs[level]);

    const float4 a = *(const float4*)(ws + f1offs[level] + p * D + ln * 4);
    const float cx = cp[p];
    const float cy = cp[npix + p];
    const int fx = (int)floorf(cx), fy = (int)floorf(cy);
    float* Gout = ws + OFF_G + gp * 100;

    int g = (hw & 3) * 25;
#pragma unroll 5
    for (int i = 0; i < 25; ++i, ++g) {
        int gy = g / 10;
        int gx = g - gy * 10;
        int iy = min(max(fy - 4 + gy, 0), Hl - 1);
        int ix = min(max(fx - 4 + gx, 0), Wl - 1);
        const float4 v = *(const float4*)(f2t + (iy * Wl + ix) * D + ln * 4);
        float s = (a.x * v.x + a.y * v.y) + (a.z * v.z + a.w * v.w);
#pragma unroll
        for (int off = 16; off; off >>= 1) s += __shfl_xor(s, off);
        if (ln == 0) Gout[g] = s;
    }
}

// ---------------------------------------------------------------------------
// K3: combine. Block = 64 consecutive pixels; G staged in LDS; coalesced
// stores over 64 consecutive p per k.
// ---------------------------------------------------------------------------
__global__ __launch_bounds__(256) void k_combine(const float* __restrict__ coords0,
                                                 const float* __restrict__ ws,
                                                 float* __restrict__ out) {
    __shared__ float Gs[64 * 101];
    __shared__ float cxs[64], cys[64];

    const int b = blockIdx.x;
    const int gp0 = b * 64;
    const int t = threadIdx.x;
    const int coffs[4]  = {0, OFF_C1, OFF_C2, OFF_C3};
    const int outoffs[4] = {OUT_L0, OUT_L1, OUT_L2, OUT_L3};

    for (int it = 0; it < 25; ++it) {
        int e = t + it * 256;                 // 0..6399
        int px = e / 100, g = e - px * 100;
        if (gp0 + px < 8160) Gs[px * 101 + g] = ws[OFF_G + (gp0 + px) * 100 + g];
    }
    if (t < 64 && gp0 + t < 8160) {
        int level, p;
        gp_to_level(gp0 + t, level, p);
        const float* cp = (level == 0) ? coords0 : (ws + coffs[level]);
        int npix = (H0 >> level) * (W0 >> level);
        cxs[t] = cp[p];
        cys[t] = cp[npix + p];
    }
    __syncthreads();

    const int px = t & 63;
    const int gp = gp0 + px;
    if (gp >= 8160) return;
    int level, p;
    gp_to_level(gp, level, p);
    const int Hl = H0 >> level, Wl = W0 >> level;
    const int npix = Hl * Wl;
    float* outp = out + outoffs[level] + p;
    const float cx = cxs[px], cy = cys[px];
    const float Wm1 = (float)(Wl - 1), Hm1 = (float)(Hl - 1);
    const float* Gp = &Gs[px * 101];

    for (int k = t >> 6; k < 81; k += 4) {
        int dxi = k / 9, dyi = k - (k / 9) * 9;
        float x = fminf(fmaxf(cx + (float)(dxi - 4), 0.0f), Wm1);
        float y = fminf(fmaxf(cy + (float)(dyi - 4), 0.0f), Hm1);
        float wx1 = x - floorf(x), wx0 = 1.0f - wx1;
        float wy1 = y - floorf(y), wy0 = 1.0f - wy1;
        int g00 = dyi * 10 + dxi;
        float v = wx0 * wy0 * Gp[g00]      + wx1 * wy0 * Gp[g00 + 1]
                + wx0 * wy1 * Gp[g00 + 10] + wx1 * wy1 * Gp[g00 + 11];
        outp[k * npix] = v * INV_SQRT_D;
    }
}

// ---------------------------------------------------------------------------
extern "C" void kernel_launch(void* const* d_in, const int* in_sizes, int n_in,
                              void* d_out, int out_size, void* d_ws, size_t ws_size,
                              hipStream_t stream) {
    const float* fmap1  = (const float*)d_in[0];
    const float* fmap2  = (const float*)d_in[1];
    const float* coords = (const float*)d_in[2];
    float* out = (float*)d_out;
    float* ws = (float*)d_ws;

    k_prep<<<dim3(400), dim3(256), 0, stream>>>(fmap1, fmap2, coords, ws);
    k_dots<<<dim3(4080), dim3(256), 0, stream>>>(coords, ws);
    k_combine<<<dim3(128), dim3(256), 0, stream>>>(coords, ws, out);
}

// Round 5
// 129.270 us; speedup vs baseline: 1.4223x; 1.0109x over previous
//
#include <hip/hip_runtime.h>

// Problem constants (B=1, D=128, H=64, W=96, 4 levels, radius 4)
#define D 128
#define H0 64
#define W0 96
#define HW0 6144
#define INV_SQRT_D 0.08838834764831843f

// Workspace layout (float offsets)
#define OFF_F1T0 0
#define OFF_F2T0 786432
#define OFF_F1T1 1572864
#define OFF_F2T1 1769472
#define OFF_F1T2 1966080
#define OFF_F2T2 2015232
#define OFF_F1T3 2064384
#define OFF_F2T3 2076672
#define OFF_C1   2088960
#define OFF_C2   2092032
#define OFF_C3   2092800
#define OFF_G    2092992   // 8160*100 floats

// Output offsets (floats)
#define OUT_L0 0
#define OUT_L1 497664
#define OUT_L2 622080
#define OUT_L3 653184

__device__ __forceinline__ void gp_to_level(int gp, int& level, int& p) {
    if (gp < 6144)      { level = 0; p = gp; }
    else if (gp < 7680) { level = 1; p = gp - 6144; }
    else if (gp < 8064) { level = 2; p = gp - 7680; }
    else                { level = 3; p = gp - 8064; }
}

// ---------------------------------------------------------------------------
// K1: fused tile transpose + pools (blocks 0..383, d-split) + coords resize
// (blocks 384..399).
// ---------------------------------------------------------------------------
__global__ __launch_bounds__(256) void k_prep(const float* __restrict__ f1,
                                              const float* __restrict__ f2,
                                              const float* __restrict__ coords,
                                              float* __restrict__ ws) {
    const int b = blockIdx.x;
    const int t = threadIdx.x;
    if (b < 384) {
        __shared__ float T[64 * 69];    // [pixel_local][d_local], stride 69
        const int m = b / 192;
        const int rb = b - m * 192;
        const int tix = rb >> 1;        // 0..95
        const int dh = rb & 1;          // d half
        const int tr = tix / 12, tc = tix - (tix / 12) * 12;
        const float* in = (m ? f2 : f1) + dh * 64 * HW0;

        const int l = t & 63;
        const int gbase = (tr * 8 + (l >> 3)) * W0 + tc * 8 + (l & 7);
#pragma unroll 4
        for (int pass = 0; pass < 16; ++pass) {
            int d = pass * 4 + (t >> 6);
            T[l * 69 + d] = in[d * HW0 + gbase];
        }
        __syncthreads();

        float* o0 = ws + (m ? OFF_F2T0 : OFF_F1T0) + dh * 64;
#pragma unroll 4
        for (int pass = 0; pass < 16; ++pass) {
            int e = t + pass * 256;
            int pl = e >> 6, c = e & 63;
            int gp = (tr * 8 + (pl >> 3)) * W0 + tc * 8 + (pl & 7);
            o0[gp * D + c] = T[pl * 69 + c];
        }
        float* o1 = ws + (m ? OFF_F2T1 : OFF_F1T1) + dh * 64;
#pragma unroll
        for (int pass = 0; pass < 4; ++pass) {
            int e = t + pass * 256;
            int d = e & 63, p1 = e >> 6;            // p1 0..15
            int i1 = p1 >> 2, j1 = p1 & 3;
            int l00 = (i1 * 2) * 8 + j1 * 2;
            float v = T[l00 * 69 + d] + T[(l00 + 1) * 69 + d]
                    + T[(l00 + 8) * 69 + d] + T[(l00 + 9) * 69 + d];
            o1[((tr * 4 + i1) * 48 + tc * 4 + j1) * D + d] = 0.25f * v;
        }
        float* o2 = ws + (m ? OFF_F2T2 : OFF_F1T2) + dh * 64;
        {
            int d = t & 63, p2 = t >> 6;            // p2 0..3
            int i2 = p2 >> 1, j2 = p2 & 1;
            float acc = 0.0f;
#pragma unroll
            for (int a = 0; a < 4; ++a)
#pragma unroll
                for (int c2 = 0; c2 < 4; ++c2)
                    acc += T[((i2 * 4 + a) * 8 + j2 * 4 + c2) * 69 + d];
            o2[((tr * 2 + i2) * 24 + tc * 2 + j2) * D + d] = acc * 0.0625f;
        }
        float* o3 = ws + (m ? OFF_F2T3 : OFF_F1T3) + dh * 64;
        if (t < 64) {
            float acc = 0.0f;
            for (int l2 = 0; l2 < 64; ++l2) acc += T[l2 * 69 + t];
            o3[(tr * 12 + tc) * D + t] = acc * 0.015625f;
        }
    } else {
        // coords resize (jax.image.resize linear, antialias=True) + /2^l
        int idx = (b - 384) * 256 + t;
        if (idx >= 4032) return;
        int level, r = idx;
        if (r < 3072) { level = 1; }
        else if (r < 3840) { level = 2; r -= 3072; }
        else { level = 3; r -= 3840; }
        const int Hl = H0 >> level, Wl = W0 >> level;
        const float ff = (float)(1 << level);
        const int npix = Hl * Wl;
        const int ch = r / npix;
        const int rem = r - ch * npix;
        const int ho = rem / Wl, wo = rem - (rem / Wl) * Wl;

        const float sfy = (ho + 0.5f) * ff - 0.5f;
        const float sfx = (wo + 0.5f) * ff - 0.5f;
        int ylo = max(0, (int)ceilf(sfy - ff));
        int yhi = min(H0 - 1, (int)floorf(sfy + ff));
        int xlo = max(0, (int)ceilf(sfx - ff));
        int xhi = min(W0 - 1, (int)floorf(sfx + ff));

        float acc = 0.0f, wsum_y = 0.0f, wsum_x = 0.0f;
        for (int iy = ylo; iy <= yhi; ++iy) {
            float wy = fmaxf(1.0f - fabsf(sfy - (float)iy) / ff, 0.0f);
            wsum_y += wy;
            float rowacc = 0.0f;
            for (int ix = xlo; ix <= xhi; ++ix) {
                float wx = fmaxf(1.0f - fabsf(sfx - (float)ix) / ff, 0.0f);
                if (iy == ylo) wsum_x += wx;
                rowacc += wx * coords[ch * HW0 + iy * W0 + ix];
            }
            acc += wy * rowacc;
        }
        float val = acc / (wsum_y * wsum_x) / ff;
        const int coffs[4] = {0, OFF_C1, OFF_C2, OFF_C3};
        ws[coffs[level] + ch * npix + ho * Wl + wo] = val;
    }
}

// ---------------------------------------------------------------------------
// K2: grid dots. One wave per pixel. 8 lanes per dot (lane sub covers 16
// consecutive d via 4 contiguous float4 loads; f1 slice in 16 regs loaded
// once). A wave computes 8 dots per iteration; one 3-step shfl_xor(1,2,4)
// reduces all 8 at once. 13 iterations cover the 100-dot grid.
// ---------------------------------------------------------------------------
__global__ __launch_bounds__(256) void k_dots(const float* __restrict__ coords0,
                                              float* __restrict__ ws) {
    const int t = threadIdx.x;
    const int gp = blockIdx.x * 4 + (t >> 6);   // wave id = pixel
    const int ln = t & 63;
    const int oct = ln >> 3;                     // 0..7 : dot within iteration
    const int sub = ln & 7;                      // 0..7 : 16-d slice

    int level, p;
    gp_to_level(gp, level, p);
    const int Hl = H0 >> level, Wl = W0 >> level;
    const int npix = Hl * Wl;

    const int f1offs[4] = {OFF_F1T0, OFF_F1T1, OFF_F1T2, OFF_F1T3};
    const int f2offs[4] = {OFF_F2T0, OFF_F2T1, OFF_F2T2, OFF_F2T3};
    const int coffs[4]  = {0, OFF_C1, OFF_C2, OFF_C3};

    const float* f2t = ws + f2offs[level];
    const float* cp = (level == 0) ? coords0 : (ws + coffs[level]);

    const float* f1p = ws + f1offs[level] + p * D + sub * 16;
    const float4 a0 = *(const float4*)(f1p + 0);
    const float4 a1 = *(const float4*)(f1p + 4);
    const float4 a2 = *(const float4*)(f1p + 8);
    const float4 a3 = *(const float4*)(f1p + 12);

    const float cx = cp[p];
    const float cy = cp[npix + p];
    const int fx = (int)floorf(cx), fy = (int)floorf(cy);
    float* Gout = ws + OFF_G + gp * 100;

#pragma unroll 2
    for (int i = 0; i < 13; ++i) {
        int g = i * 8 + oct;
        int gc = min(g, 99);
        int gy = gc / 10;
        int gx = gc - gy * 10;
        int iy = min(max(fy - 4 + gy, 0), Hl - 1);
        int ix = min(max(fx - 4 + gx, 0), Wl - 1);
        const float* row = f2t + (iy * Wl + ix) * D + sub * 16;
        const float4 v0 = *(const float4*)(row + 0);
        const float4 v1 = *(const float4*)(row + 4);
        const float4 v2 = *(const float4*)(row + 8);
        const float4 v3 = *(const float4*)(row + 12);
        float s = (a0.x * v0.x + a0.y * v0.y) + (a0.z * v0.z + a0.w * v0.w)
                + (a1.x * v1.x + a1.y * v1.y) + (a1.z * v1.z + a1.w * v1.w)
                + (a2.x * v2.x + a2.y * v2.y) + (a2.z * v2.z + a2.w * v2.w)
                + (a3.x * v3.x + a3.y * v3.y) + (a3.z * v3.z + a3.w * v3.w);
        s += __shfl_xor(s, 1);
        s += __shfl_xor(s, 2);
        s += __shfl_xor(s, 4);
        if (sub == 0 && g < 100) Gout[g] = s;
    }
}

// ---------------------------------------------------------------------------
// K3: combine. Block = 64 consecutive pixels; G staged in LDS; coalesced
// stores over 64 consecutive p per k.
// ---------------------------------------------------------------------------
__global__ __launch_bounds__(256) void k_combine(const float* __restrict__ coords0,
                                                 const float* __restrict__ ws,
                                                 float* __restrict__ out) {
    __shared__ float Gs[64 * 101];
    __shared__ float cxs[64], cys[64];

    const int b = blockIdx.x;
    const int gp0 = b * 64;
    const int t = threadIdx.x;
    const int coffs[4]  = {0, OFF_C1, OFF_C2, OFF_C3};
    const int outoffs[4] = {OUT_L0, OUT_L1, OUT_L2, OUT_L3};

    for (int it = 0; it < 25; ++it) {
        int e = t + it * 256;                 // 0..6399
        int px = e / 100, g = e - px * 100;
        if (gp0 + px < 8160) Gs[px * 101 + g] = ws[OFF_G + (gp0 + px) * 100 + g];
    }
    if (t < 64 && gp0 + t < 8160) {
        int level, p;
        gp_to_level(gp0 + t, level, p);
        const float* cp = (level == 0) ? coords0 : (ws + coffs[level]);
        int npix = (H0 >> level) * (W0 >> level);
        cxs[t] = cp[p];
        cys[t] = cp[npix + p];
    }
    __syncthreads();

    const int px = t & 63;
    const int gp = gp0 + px;
    if (gp >= 8160) return;
    int level, p;
    gp_to_level(gp, level, p);
    const int Hl = H0 >> level, Wl = W0 >> level;
    const int npix = Hl * Wl;
    float* outp = out + outoffs[level] + p;
    const float cx = cxs[px], cy = cys[px];
    const float Wm1 = (float)(Wl - 1), Hm1 = (float)(Hl - 1);
    const float* Gp = &Gs[px * 101];

    for (int k = t >> 6; k < 81; k += 4) {
        int dxi = k / 9, dyi = k - (k / 9) * 9;
        float x = fminf(fmaxf(cx + (float)(dxi - 4), 0.0f), Wm1);
        float y = fminf(fmaxf(cy + (float)(dyi - 4), 0.0f), Hm1);
        float wx1 = x - floorf(x), wx0 = 1.0f - wx1;
        float wy1 = y - floorf(y), wy0 = 1.0f - wy1;
        int g00 = dyi * 10 + dxi;
        float v = wx0 * wy0 * Gp[g00]      + wx1 * wy0 * Gp[g00 + 1]
                + wx0 * wy1 * Gp[g00 + 10] + wx1 * wy1 * Gp[g00 + 11];
        outp[k * npix] = v * INV_SQRT_D;
    }
}

// ---------------------------------------------------------------------------
extern "C" void kernel_launch(void* const* d_in, const int* in_sizes, int n_in,
                              void* d_out, int out_size, void* d_ws, size_t ws_size,
                              hipStream_t stream) {
    const float* fmap1  = (const float*)d_in[0];
    const float* fmap2  = (const float*)d_in[1];
    const float* coords = (const float*)d_in[2];
    float* out = (float*)d_out;
    float* ws = (float*)d_ws;

    k_prep<<<dim3(400), dim3(256), 0, stream>>>(fmap1, fmap2, coords, ws);
    k_dots<<<dim3(2040), dim3(256), 0, stream>>>(coords, ws);
    k_combine<<<dim3(128), dim3(256), 0, stream>>>(coords, ws, out);
}

// Round 6
// 119.616 us; speedup vs baseline: 1.5371x; 1.0807x over previous
//
#include <hip/hip_runtime.h>

// Problem constants (B=1, D=128, H=64, W=96, 4 levels, radius 4)
#define D 128
#define H0 64
#define W0 96
#define HW0 6144
#define INV_SQRT_D 0.08838834764831843f

// Workspace layout (float offsets)
#define OFF_F1T0 0
#define OFF_F2T0 786432
#define OFF_F1T1 1572864
#define OFF_F2T1 1769472
#define OFF_F1T2 1966080
#define OFF_F2T2 2015232
#define OFF_F1T3 2064384
#define OFF_F2T3 2076672
#define OFF_C1   2088960
#define OFF_C2   2092032
#define OFF_C3   2092800
#define OFF_G    2092992   // 8160*100 floats

// Output offsets (floats)
#define OUT_L0 0
#define OUT_L1 497664
#define OUT_L2 622080
#define OUT_L3 653184

__device__ __forceinline__ void gp_to_level(int gp, int& level, int& p) {
    if (gp < 6144)      { level = 0; p = gp; }
    else if (gp < 7680) { level = 1; p = gp - 6144; }
    else if (gp < 8064) { level = 2; p = gp - 7680; }
    else                { level = 3; p = gp - 8064; }
}

// ---------------------------------------------------------------------------
// K1: fused tile transpose + pools (blocks 0..383, d-split) + coords resize
// (blocks 384..399).
// ---------------------------------------------------------------------------
__global__ __launch_bounds__(256) void k_prep(const float* __restrict__ f1,
                                              const float* __restrict__ f2,
                                              const float* __restrict__ coords,
                                              float* __restrict__ ws) {
    const int b = blockIdx.x;
    const int t = threadIdx.x;
    if (b < 384) {
        __shared__ float T[64 * 69];    // [pixel_local][d_local], stride 69
        const int m = b / 192;
        const int rb = b - m * 192;
        const int tix = rb >> 1;        // 0..95
        const int dh = rb & 1;          // d half
        const int tr = tix / 12, tc = tix - (tix / 12) * 12;
        const float* in = (m ? f2 : f1) + dh * 64 * HW0;

        const int l = t & 63;
        const int gbase = (tr * 8 + (l >> 3)) * W0 + tc * 8 + (l & 7);
#pragma unroll 4
        for (int pass = 0; pass < 16; ++pass) {
            int d = pass * 4 + (t >> 6);
            T[l * 69 + d] = in[d * HW0 + gbase];
        }
        __syncthreads();

        float* o0 = ws + (m ? OFF_F2T0 : OFF_F1T0) + dh * 64;
#pragma unroll 4
        for (int pass = 0; pass < 16; ++pass) {
            int e = t + pass * 256;
            int pl = e >> 6, c = e & 63;
            int gp = (tr * 8 + (pl >> 3)) * W0 + tc * 8 + (pl & 7);
            o0[gp * D + c] = T[pl * 69 + c];
        }
        float* o1 = ws + (m ? OFF_F2T1 : OFF_F1T1) + dh * 64;
#pragma unroll
        for (int pass = 0; pass < 4; ++pass) {
            int e = t + pass * 256;
            int d = e & 63, p1 = e >> 6;            // p1 0..15
            int i1 = p1 >> 2, j1 = p1 & 3;
            int l00 = (i1 * 2) * 8 + j1 * 2;
            float v = T[l00 * 69 + d] + T[(l00 + 1) * 69 + d]
                    + T[(l00 + 8) * 69 + d] + T[(l00 + 9) * 69 + d];
            o1[((tr * 4 + i1) * 48 + tc * 4 + j1) * D + d] = 0.25f * v;
        }
        float* o2 = ws + (m ? OFF_F2T2 : OFF_F1T2) + dh * 64;
        {
            int d = t & 63, p2 = t >> 6;            // p2 0..3
            int i2 = p2 >> 1, j2 = p2 & 1;
            float acc = 0.0f;
#pragma unroll
            for (int a = 0; a < 4; ++a)
#pragma unroll
                for (int c2 = 0; c2 < 4; ++c2)
                    acc += T[((i2 * 4 + a) * 8 + j2 * 4 + c2) * 69 + d];
            o2[((tr * 2 + i2) * 24 + tc * 2 + j2) * D + d] = acc * 0.0625f;
        }
        float* o3 = ws + (m ? OFF_F2T3 : OFF_F1T3) + dh * 64;
        if (t < 64) {
            float acc = 0.0f;
            for (int l2 = 0; l2 < 64; ++l2) acc += T[l2 * 69 + t];
            o3[(tr * 12 + tc) * D + t] = acc * 0.015625f;
        }
    } else {
        // coords resize (jax.image.resize linear, antialias=True) + /2^l
        int idx = (b - 384) * 256 + t;
        if (idx >= 4032) return;
        int level, r = idx;
        if (r < 3072) { level = 1; }
        else if (r < 3840) { level = 2; r -= 3072; }
        else { level = 3; r -= 3840; }
        const int Hl = H0 >> level, Wl = W0 >> level;
        const float ff = (float)(1 << level);
        const int npix = Hl * Wl;
        const int ch = r / npix;
        const int rem = r - ch * npix;
        const int ho = rem / Wl, wo = rem - (rem / Wl) * Wl;

        const float sfy = (ho + 0.5f) * ff - 0.5f;
        const float sfx = (wo + 0.5f) * ff - 0.5f;
        int ylo = max(0, (int)ceilf(sfy - ff));
        int yhi = min(H0 - 1, (int)floorf(sfy + ff));
        int xlo = max(0, (int)ceilf(sfx - ff));
        int xhi = min(W0 - 1, (int)floorf(sfx + ff));

        float acc = 0.0f, wsum_y = 0.0f, wsum_x = 0.0f;
        for (int iy = ylo; iy <= yhi; ++iy) {
            float wy = fmaxf(1.0f - fabsf(sfy - (float)iy) / ff, 0.0f);
            wsum_y += wy;
            float rowacc = 0.0f;
            for (int ix = xlo; ix <= xhi; ++ix) {
                float wx = fmaxf(1.0f - fabsf(sfx - (float)ix) / ff, 0.0f);
                if (iy == ylo) wsum_x += wx;
                rowacc += wx * coords[ch * HW0 + iy * W0 + ix];
            }
            acc += wy * rowacc;
        }
        float val = acc / (wsum_y * wsum_x) / ff;
        const int coffs[4] = {0, OFF_C1, OFF_C2, OFF_C3};
        ws[coffs[level] + ch * npix + ho * Wl + wo] = val;
    }
}

// ---------------------------------------------------------------------------
// K2: grid dots. One wave per pixel. 8 lanes (sub=ln&7) per dot with
// INTERLEAVED d-slicing: lane sub takes d = j*32 + sub*4 + {0..3}, j=0..3,
// so lanes 0..7 of an oct read one contiguous 128B segment per load instr
// (8 segments/wave-instr total — minimal for 8 distinct rows). 8 dots per
// iteration (oct=ln>>3), one 3-step shfl_xor(1,2,4) reduces all 8.
// ---------------------------------------------------------------------------
__global__ __launch_bounds__(256) void k_dots(const float* __restrict__ coords0,
                                              float* __restrict__ ws) {
    const int t = threadIdx.x;
    const int gp = blockIdx.x * 4 + (t >> 6);   // wave id = pixel
    const int ln = t & 63;
    const int oct = ln >> 3;                     // 0..7 : dot within iteration
    const int sub = ln & 7;                      // 0..7 : interleaved d slice

    int level, p;
    gp_to_level(gp, level, p);
    const int Hl = H0 >> level, Wl = W0 >> level;
    const int npix = Hl * Wl;

    const int f1offs[4] = {OFF_F1T0, OFF_F1T1, OFF_F1T2, OFF_F1T3};
    const int f2offs[4] = {OFF_F2T0, OFF_F2T1, OFF_F2T2, OFF_F2T3};
    const int coffs[4]  = {0, OFF_C1, OFF_C2, OFF_C3};

    const float* f2t = ws + f2offs[level];
    const float* cp = (level == 0) ? coords0 : (ws + coffs[level]);

    // f1 slice: d = j*32 + sub*4 .. +3 (contiguous across sub within each j)
    const float* f1p = ws + f1offs[level] + p * D + sub * 4;
    const float4 a0 = *(const float4*)(f1p + 0);
    const float4 a1 = *(const float4*)(f1p + 32);
    const float4 a2 = *(const float4*)(f1p + 64);
    const float4 a3 = *(const float4*)(f1p + 96);

    const float cx = cp[p];
    const float cy = cp[npix + p];
    const int fx = (int)floorf(cx), fy = (int)floorf(cy);
    float* Gout = ws + OFF_G + gp * 100;

#pragma unroll 2
    for (int i = 0; i < 13; ++i) {
        int g = i * 8 + oct;
        int gc = min(g, 99);
        int gy = gc / 10;
        int gx = gc - gy * 10;
        int iy = min(max(fy - 4 + gy, 0), Hl - 1);
        int ix = min(max(fx - 4 + gx, 0), Wl - 1);
        const float* row = f2t + (iy * Wl + ix) * D + sub * 4;
        const float4 v0 = *(const float4*)(row + 0);
        const float4 v1 = *(const float4*)(row + 32);
        const float4 v2 = *(const float4*)(row + 64);
        const float4 v3 = *(const float4*)(row + 96);
        float s = (a0.x * v0.x + a0.y * v0.y) + (a0.z * v0.z + a0.w * v0.w)
                + (a1.x * v1.x + a1.y * v1.y) + (a1.z * v1.z + a1.w * v1.w)
                + (a2.x * v2.x + a2.y * v2.y) + (a2.z * v2.z + a2.w * v2.w)
                + (a3.x * v3.x + a3.y * v3.y) + (a3.z * v3.z + a3.w * v3.w);
        s += __shfl_xor(s, 1);
        s += __shfl_xor(s, 2);
        s += __shfl_xor(s, 4);
        if (sub == 0 && g < 100) Gout[g] = s;
    }
}

// ---------------------------------------------------------------------------
// K3: combine. Block = 64 consecutive pixels; G staged in LDS; coalesced
// stores over 64 consecutive p per k.
// ---------------------------------------------------------------------------
__global__ __launch_bounds__(256) void k_combine(const float* __restrict__ coords0,
                                                 const float* __restrict__ ws,
                                                 float* __restrict__ out) {
    __shared__ float Gs[64 * 101];
    __shared__ float cxs[64], cys[64];

    const int b = blockIdx.x;
    const int gp0 = b * 64;
    const int t = threadIdx.x;
    const int coffs[4]  = {0, OFF_C1, OFF_C2, OFF_C3};
    const int outoffs[4] = {OUT_L0, OUT_L1, OUT_L2, OUT_L3};

    for (int it = 0; it < 25; ++it) {
        int e = t + it * 256;                 // 0..6399
        int px = e / 100, g = e - px * 100;
        if (gp0 + px < 8160) Gs[px * 101 + g] = ws[OFF_G + (gp0 + px) * 100 + g];
    }
    if (t < 64 && gp0 + t < 8160) {
        int level, p;
        gp_to_level(gp0 + t, level, p);
        const float* cp = (level == 0) ? coords0 : (ws + coffs[level]);
        int npix = (H0 >> level) * (W0 >> level);
        cxs[t] = cp[p];
        cys[t] = cp[npix + p];
    }
    __syncthreads();

    const int px = t & 63;
    const int gp = gp0 + px;
    if (gp >= 8160) return;
    int level, p;
    gp_to_level(gp, level, p);
    const int Hl = H0 >> level, Wl = W0 >> level;
    const int npix = Hl * Wl;
    float* outp = out + outoffs[level] + p;
    const float cx = cxs[px], cy = cys[px];
    const float Wm1 = (float)(Wl - 1), Hm1 = (float)(Hl - 1);
    const float* Gp = &Gs[px * 101];

    for (int k = t >> 6; k < 81; k += 4) {
        int dxi = k / 9, dyi = k - (k / 9) * 9;
        float x = fminf(fmaxf(cx + (float)(dxi - 4), 0.0f), Wm1);
        float y = fminf(fmaxf(cy + (float)(dyi - 4), 0.0f), Hm1);
        float wx1 = x - floorf(x), wx0 = 1.0f - wx1;
        float wy1 = y - floorf(y), wy0 = 1.0f - wy1;
        int g00 = dyi * 10 + dxi;
        float v = wx0 * wy0 * Gp[g00]      + wx1 * wy0 * Gp[g00 + 1]
                + wx0 * wy1 * Gp[g00 + 10] + wx1 * wy1 * Gp[g00 + 11];
        outp[k * npix] = v * INV_SQRT_D;
    }
}

// ---------------------------------------------------------------------------
extern "C" void kernel_launch(void* const* d_in, const int* in_sizes, int n_in,
                              void* d_out, int out_size, void* d_ws, size_t ws_size,
                              hipStream_t stream) {
    const float* fmap1  = (const float*)d_in[0];
    const float* fmap2  = (const float*)d_in[1];
    const float* coords = (const float*)d_in[2];
    float* out = (float*)d_out;
    float* ws = (float*)d_ws;

    k_prep<<<dim3(400), dim3(256), 0, stream>>>(fmap1, fmap2, coords, ws);
    k_dots<<<dim3(2040), dim3(256), 0, stream>>>(coords, ws);
    k_combine<<<dim3(128), dim3(256), 0, stream>>>(coords, ws, out);
}